// Round 1
// 144.110 us; speedup vs baseline: 1.0120x; 1.0120x over previous
//
#include <hip/hip_runtime.h>
#include <math.h>

// LeNet-5 fused forward, G=4 images per 256-thread block, 2048 blocks, f16 MFMA + fdot2.
// Round 12: phase B restructured img-outer (18 live h2v, no rematerialized LDS re-reads),
//           squash -> 5-op branchless form (1.7159 - 3.4318/(1+e^{4x/3})).
typedef _Float16 h16;
typedef h16  h8v __attribute__((ext_vector_type(8)));
typedef h16  h4v __attribute__((ext_vector_type(4)));
typedef h16  h2v __attribute__((ext_vector_type(2)));
typedef float f4v __attribute__((ext_vector_type(4)));
typedef unsigned int u32;

#if defined(__has_builtin)
#if __has_builtin(__builtin_amdgcn_fdot2)
#define FDOT2(a,b,c) __builtin_amdgcn_fdot2((a),(b),(c),false)
#endif
#endif
#ifndef FDOT2
#define FDOT2(a,b,c) ((c) + (float)(a).x*(float)(b).x + (float)(a).y*(float)(b).y)
#endif

// ws float offsets
#define WS_K1H  0       // 216 h16: folded C1+S2 6x6x6 packed f16 pairs
#define WS_B1   216     // 6 f32
#define WS_B3   224     // 16 f32
#define WS_W3H  240     // [6][16][48] f16 (C3 B^T, k=u*6+v, pad 36..47=0)
#define WS_W5H  2544    // [16][128][32] f16 (C5 B^T, k=r*5+c, pads 0)
#define WS_F6H  35312   // [96][128] f16 (F6 B^T, pads 0)
#define WS_RBFT 41456   // 840 f32: rbf transposed [10][84]

// LDS byte offsets (6 barriers; lifetimes as round 9)
#define L_B3    0
#define L_C5B   64
#define L_F6B   576
#define L_S2H   960
#define L_A5    960
#define L_HB    960
#define L_XPADH 14784
#define L_S4    20160
#define L_A6    20160
#define LDS_TOTAL 26304

__device__ const unsigned char MASK16[16] = {7,14,28,56,49,35,15,30,60,57,51,39,27,54,45,63};

// 1.7159*tanh((2/3)x) = 1.7159 - 3.4318/(1 + e^{(4/3)x})
// e^{(4/3)x} -> inf for large x gives rcp->0 (correct saturation); ->0 for very negative x.
__device__ __forceinline__ float squash(float x) {
    float E = __expf(1.33333333f * x);          // v_mul (log2e fold) + v_exp
    return 1.7159f - 3.4318f * __builtin_amdgcn_rcpf(1.0f + E);
}

__global__ __launch_bounds__(256) void prep_kernel(
    const float* __restrict__ c1_w, const float* __restrict__ c1_b,
    const float* __restrict__ s2_w, const float* __restrict__ s2_b,
    const float* __restrict__ c3_w, const float* __restrict__ c3_b,
    const float* __restrict__ s4_w, const float* __restrict__ s4_b,
    const float* __restrict__ c5_w, const float* __restrict__ f6_w,
    const float* __restrict__ rbf_w,
    float* __restrict__ ws)
{
    const int gid = blockIdx.x * 256 + threadIdx.x;
    const int gstr = gridDim.x * 256;
    h16* K1H = (h16*)ws;
    for (int idx = gid; idx < 216; idx += gstr) {
        int c = idx / 36, r = idx - c * 36;
        int u = r / 6, v = r - u * 6;
        float s = 0.f;
        #pragma unroll
        for (int dy = 0; dy < 2; ++dy)
            #pragma unroll
            for (int dx = 0; dx < 2; ++dx) {
                int ky = u - dy, kx = v - dx;
                if (ky >= 0 && ky < 5 && kx >= 0 && kx < 5)
                    s += c1_w[(c * 5 + ky) * 5 + kx];
            }
        K1H[idx] = (h16)(0.25f * s * s2_w[c]);
    }
    if (gid < 6)  ws[WS_B1 + gid] = s2_w[gid] * c1_b[gid] + s2_b[gid];
    if (gid < 16) ws[WS_B3 + gid] = s4_w[gid] * c3_b[gid] + s4_b[gid];
    h16* W3H = (h16*)(ws + WS_W3H);
    for (int idx = gid; idx < 4608; idx += gstr) {
        int i = idx / 768, r = idx - i * 768;
        int n = r / 48, k = r - n * 48;
        float val = 0.f;
        if (k < 36) {
            int u = k / 6, v = k - u * 6;
            float s = 0.f;
            #pragma unroll
            for (int dy = 0; dy < 2; ++dy)
                #pragma unroll
                for (int dx = 0; dx < 2; ++dx) {
                    int ky = u - dy, kx = v - dx;
                    if (ky >= 0 && ky < 5 && kx >= 0 && kx < 5)
                        s += c3_w[((n * 6 + i) * 5 + ky) * 5 + kx];
                }
            val = ((MASK16[n] >> i) & 1) ? 0.25f * s4_w[n] * s : 0.f;
        }
        W3H[idx] = (h16)val;
    }
    h16* W5H = (h16*)(ws + WS_W5H);
    for (int idx = gid; idx < 65536; idx += gstr) {
        int i = idx >> 12, r = idx & 4095;
        int n = r >> 5, k = r & 31;
        float val = (n < 120 && k < 25) ? c5_w[n * 400 + i * 25 + k] : 0.f;
        W5H[idx] = (h16)val;
    }
    h16* F6H = (h16*)(ws + WS_F6H);
    for (int idx = gid; idx < 12288; idx += gstr) {
        int n = idx >> 7, k = idx & 127;
        float val = (n < 84 && k < 120) ? f6_w[n * 120 + k] : 0.f;
        F6H[idx] = (h16)val;
    }
    for (int idx = gid; idx < 840; idx += gstr) {
        int k = idx / 10, c = idx - k * 10;
        ws[WS_RBFT + c * 84 + k] = rbf_w[idx];
    }
}

__global__ __launch_bounds__(256, 6) void lenet_kernel(
    const float* __restrict__ x,
    const float* __restrict__ c5_b, const float* __restrict__ f6_b,
    const float* __restrict__ ws,
    float* __restrict__ out)
{
    __shared__ __align__(16) char smem[LDS_TOTAL];
    float* s_b3  = (float*)(smem + L_B3);
    float* s_c5b = (float*)(smem + L_C5B);
    float* s_f6b = (float*)(smem + L_F6B);
    h16*  XPADH  = (h16*)(smem + L_XPADH);
    h16*  S2H    = (h16*)(smem + L_S2H);
    h16*  S4     = (h16*)(smem + L_S4);
    h16*  A5     = (h16*)(smem + L_A5);
    h16*  A6     = (h16*)(smem + L_A6);
    float* HB    = (float*)(smem + L_HB);

    const int tid  = threadIdx.x;
    const int wave = __builtin_amdgcn_readfirstlane(tid >> 6);
    const int lane = tid & 63;
    const int quad = lane >> 4;
    const int lr   = lane & 15;

    // ---- stage constants + input (replicate pad, f16 packed pairs, pitch 40) ----
    if (tid < 16)  s_b3[tid] = ws[WS_B3 + tid];
    if (tid < 128) s_c5b[tid] = (tid < 120) ? c5_b[tid] : 0.f;
    if (tid < 96)  s_f6b[tid] = (tid < 84) ? f6_b[tid] : 0.f;
    const float* xb = x + (size_t)blockIdx.x * 4096;
    for (int idx = tid; idx < 2880; idx += 256) {
        int img = idx / 720, r2 = idx - img * 720;
        int u = r2 / 20, v2 = r2 - u * 20;
        int sy = min(max(u - 2, 0), 31);
        int c0 = min(max(2 * v2 - 2, 0), 31);
        int c1 = min(max(2 * v2 - 1, 0), 31);
        const float* xr = xb + img * 1024 + sy * 32;
        h2v hv; hv.x = (h16)xr[c0]; hv.y = (h16)xr[c1];
        *(h2v*)(XPADH + img * 1440 + u * 40 + 2 * v2) = hv;
    }
    __syncthreads();   // [1] XPADH + consts ready

    // ======== B: C1+S2+act via fdot2 -> S2H f16 ========
    // Round 12: img-outer with unroll(1) so only 18 h2v window values are live at a time.
    // (Previous win2[4][18] = 72 VGPRs exceeded the allocation -> compiler rematerialized
    //  the LDS reads inside the channel loop: ~432 ds_read_b32/thread instead of 72.)
    {
        int py = tid >> 4, px = tid & 15;
        const h2v* K1H = (const h2v*)ws;  // [6][18], lane-uniform -> SGPRs
        #pragma unroll 1
        for (int img = 0; img < 4; ++img) {
            const h16* basep = XPADH + img * 1440 + (2 * py) * 40 + 2 * px;
            h2v win2[18];
            #pragma unroll
            for (int u = 0; u < 6; ++u)
                #pragma unroll
                for (int p = 0; p < 3; ++p)
                    win2[u * 3 + p] = *(const h2v*)(basep + u * 40 + 2 * p);
            #pragma unroll
            for (int c = 0; c < 6; ++c) {
                float acc = ws[WS_B1 + c];
                #pragma unroll
                for (int j = 0; j < 18; ++j)
                    acc = FDOT2(win2[j], K1H[c * 18 + j], acc);
                S2H[img * 1728 + c * 288 + py * 18 + px] = (h16)squash(acc);
            }
        }
    }
    __syncthreads();   // [2] S2H ready

    // ======== C: C3+S4 via MFMA, A-fragments direct from S2H; hand-unrolled, no arrays ========
    {
        const h16* W3H = (const h16*)(ws + WS_W3H);
        // computed per-quad k-slice offsets: load j covers k=8*quad+2*j; off=(k/6)*18+(k%6)
        int o0, o1, o2, o3;
        {
            int k0 = 8 * quad;
            int u0 = k0 / 6, v0 = k0 - u0 * 6;  o0 = u0 * 18 + v0;
            int k1 = k0 + 2;
            int u1 = k1 / 6, v1 = k1 - u1 * 6;  o1 = u1 * 18 + v1;
            int k2 = k0 + 4;
            int u2 = k2 / 6, v2 = k2 - u2 * 6;  o2 = u2 * 18 + v2;
            int k3 = k0 + 6;
            int u3 = k3 / 6, v3 = k3 - u3 * 6;  o3 = u3 * 18 + v3;
        }
        // row geometry for the three M-tiles (Mt = wave, wave+4, 8[wave0 only])
        int baseh0, baseh1, baseh2;
        {
            int m0 = wave * 16 + lr;
            int i0 = m0 / 36, p0 = m0 - i0 * 36;
            baseh0 = i0 * 1728 + (2 * (p0 / 6)) * 18 + 2 * (p0 % 6);
            int m1 = (wave + 4) * 16 + lr;
            int i1 = m1 / 36, p1 = m1 - i1 * 36;
            baseh1 = i1 * 1728 + (2 * (p1 / 6)) * 18 + 2 * (p1 % 6);
            int m2 = 128 + lr;   // Mt=8 (used by wave 0 only)
            int i2 = m2 / 36, p2 = m2 - i2 * 36;
            baseh2 = i2 * 1728 + (2 * (p2 / 6)) * 18 + 2 * (p2 % 6);
        }
        f4v cacc0 = {}, cacc1 = {}, cacc2 = {};
        const bool w0 = (wave == 0);
        #pragma unroll
        for (int i = 0; i < 6; ++i) {
            const h16* bbase = W3H + i * 768 + lr * 48;
            h8v w3a = *(const h8v*)(bbase + quad * 8);
            h4v w3b = *(const h4v*)(bbase + 32 + quad * 4);
            const h16* bp0 = S2H + baseh0 + i * 288;
            {
                union { u32 u[4]; h8v h; } av;
                av.u[0] = *(const u32*)(bp0 + o0);
                av.u[1] = *(const u32*)(bp0 + o1);
                av.u[2] = *(const u32*)(bp0 + o2);
                av.u[3] = *(const u32*)(bp0 + o3);
                cacc0 = __builtin_amdgcn_mfma_f32_16x16x32_f16(av.h, w3a, cacc0, 0, 0, 0);
                union { u32 u[2]; h4v h; } av2;
                av2.u[0] = *(const u32*)(bp0 + 92);
                av2.u[1] = *(const u32*)(bp0 + 94);
                cacc0 = __builtin_amdgcn_mfma_f32_16x16x16f16(av2.h, w3b, cacc0, 0, 0, 0);
            }
            const h16* bp1 = S2H + baseh1 + i * 288;
            {
                union { u32 u[4]; h8v h; } av;
                av.u[0] = *(const u32*)(bp1 + o0);
                av.u[1] = *(const u32*)(bp1 + o1);
                av.u[2] = *(const u32*)(bp1 + o2);
                av.u[3] = *(const u32*)(bp1 + o3);
                cacc1 = __builtin_amdgcn_mfma_f32_16x16x32_f16(av.h, w3a, cacc1, 0, 0, 0);
                union { u32 u[2]; h4v h; } av2;
                av2.u[0] = *(const u32*)(bp1 + 92);
                av2.u[1] = *(const u32*)(bp1 + 94);
                cacc1 = __builtin_amdgcn_mfma_f32_16x16x16f16(av2.h, w3b, cacc1, 0, 0, 0);
            }
            if (w0) {
                const h16* bp2 = S2H + baseh2 + i * 288;
                union { u32 u[4]; h8v h; } av;
                av.u[0] = *(const u32*)(bp2 + o0);
                av.u[1] = *(const u32*)(bp2 + o1);
                av.u[2] = *(const u32*)(bp2 + o2);
                av.u[3] = *(const u32*)(bp2 + o3);
                cacc2 = __builtin_amdgcn_mfma_f32_16x16x32_f16(av.h, w3a, cacc2, 0, 0, 0);
                union { u32 u[2]; h4v h; } av2;
                av2.u[0] = *(const u32*)(bp2 + 92);
                av2.u[1] = *(const u32*)(bp2 + 94);
                cacc2 = __builtin_amdgcn_mfma_f32_16x16x16f16(av2.h, w3b, cacc2, 0, 0, 0);
            }
        }
        // epilogue: squash -> S4 @ dead-XPADH region
        float b3v = s_b3[lr];
        {
            #pragma unroll
            for (int r = 0; r < 4; ++r) {
                int m = wave * 16 + quad * 4 + r;
                int img = m / 36, pos = m - img * 36;
                S4[img * 672 + lr * 42 + pos] = (h16)squash(cacc0[r] + b3v);
            }
            #pragma unroll
            for (int r = 0; r < 4; ++r) {
                int m = (wave + 4) * 16 + quad * 4 + r;
                int img = m / 36, pos = m - img * 36;
                S4[img * 672 + lr * 42 + pos] = (h16)squash(cacc1[r] + b3v);
            }
            if (w0) {
                #pragma unroll
                for (int r = 0; r < 4; ++r) {
                    int m = 128 + quad * 4 + r;
                    int img = m / 36, pos = m - img * 36;
                    S4[img * 672 + lr * 42 + pos] = (h16)squash(cacc2[r] + b3v);
                }
            }
        }
    }
    __syncthreads();   // [3] S4 ready; all S2H reads done

    // ======== D: C5 via MFMA. GEMM [16 x 512] x [512 x 128] ========
    {
        // build A5 [16][520] (over dead S2H): thread = (m, i); reads S4 (disjoint region)
        {
            int m = tid >> 4, i = tid & 15;
            int img = m >> 2, q = m & 3, qy = q >> 1, qx = q & 1;
            const h16* s4b = S4 + img * 672 + i * 42 + qy * 6 + qx;
            h16* dst = A5 + m * 520 + i * 32;
            #pragma unroll
            for (int c = 0; c < 4; ++c) {
                h8v v;
                #pragma unroll
                for (int j = 0; j < 8; ++j) {
                    int k = c * 8 + j;
                    v[j] = (k < 25) ? s4b[(k / 5) * 6 + (k % 5)] : (h16)0.f;
                }
                *(h8v*)(dst + c * 8) = v;
            }
        }
        __syncthreads();   // [4] A5 ready
        const h16* W5H = (const h16*)(ws + WS_W5H);
        f4v dacc0 = {}, dacc1 = {};
        #pragma unroll
        for (int i = 0; i < 16; ++i) {
            h8v bf0 = *(const h8v*)(W5H + i * 4096 + (wave * 32 + lr) * 32 + quad * 8);
            h8v bf1 = *(const h8v*)(W5H + i * 4096 + (wave * 32 + 16 + lr) * 32 + quad * 8);
            h8v af0 = *(const h8v*)(A5 + lr * 520 + i * 32 + quad * 8);
            dacc0 = __builtin_amdgcn_mfma_f32_16x16x32_f16(af0, bf0, dacc0, 0, 0, 0);
            dacc1 = __builtin_amdgcn_mfma_f32_16x16x32_f16(af0, bf1, dacc1, 0, 0, 0);
        }
        // zero pad cols 120..127 of A6 (over dead S4)
        if (tid < 64) {
            int m = tid >> 2, j = tid & 3;
            *(u32*)(A6 + m * 136 + 120 + 2 * j) = 0u;
        }
        // epilogue, reference reshape: row=img*4+(n/30), col=(n%30)*4+q
        {
            int n0 = wave * 32 + lr;
            if (n0 < 120) {
                int tt = n0 / 30, cb = (n0 - tt * 30) * 4;
                float bias = s_c5b[n0];
                #pragma unroll
                for (int r = 0; r < 4; ++r) {
                    int m = quad * 4 + r;
                    A6[((m >> 2) * 4 + tt) * 136 + cb + (m & 3)] = (h16)(dacc0[r] + bias);
                }
            }
            int n1 = wave * 32 + 16 + lr;
            if (n1 < 120) {
                int tt = n1 / 30, cb = (n1 - tt * 30) * 4;
                float bias = s_c5b[n1];
                #pragma unroll
                for (int r = 0; r < 4; ++r) {
                    int m = quad * 4 + r;
                    A6[((m >> 2) * 4 + tt) * 136 + cb + (m & 3)] = (h16)(dacc1[r] + bias);
                }
            }
        }
    }
    __syncthreads();   // [5] A6 ready; all A5 reads done

    // ======== E: F6+act via MFMA. GEMM [16 x 128] x [128 x 96] ========
    {
        const h16* F6H = (const h16*)(ws + WS_F6H);
        f4v eacc0 = {}, eacc1 = {};
        const bool w2 = (wave < 2);
        #pragma unroll
        for (int kc = 0; kc < 4; ++kc) {
            h8v a8 = *(const h8v*)(A6 + lr * 136 + kc * 32 + quad * 8);
            h8v b0 = *(const h8v*)(F6H + (wave * 16 + lr) * 128 + kc * 32 + quad * 8);
            eacc0 = __builtin_amdgcn_mfma_f32_16x16x32_f16(a8, b0, eacc0, 0, 0, 0);
            if (w2) {
                h8v b1 = *(const h8v*)(F6H + ((wave + 4) * 16 + lr) * 128 + kc * 32 + quad * 8);
                eacc1 = __builtin_amdgcn_mfma_f32_16x16x32_f16(a8, b1, eacc1, 0, 0, 0);
            }
        }
        {
            int n = wave * 16 + lr;   // 0..63 < 84
            float bias = s_f6b[n];
            #pragma unroll
            for (int r = 0; r < 4; ++r) {
                int m = quad * 4 + r;
                HB[m * 88 + n] = squash(eacc0[r] + bias);   // HB over dead A5
            }
        }
        if (w2) {
            int n = (wave + 4) * 16 + lr;  // 64..95
            if (n < 84) {
                float bias = s_f6b[n];
                #pragma unroll
                for (int r = 0; r < 4; ++r) {
                    int m = quad * 4 + r;
                    HB[m * 88 + n] = squash(eacc1[r] + bias);
                }
            }
        }
    }
    __syncthreads();   // [6] HB ready

    // ======== F: RBF distances (VALU); prototypes from L2-resident rbfT ========
    if (tid < 160) {
        int m = tid / 10, cls = tid - m * 10;
        const float4* hr = (const float4*)(HB + m * 88);
        const float4* pr = (const float4*)(ws + WS_RBFT + cls * 84);
        float a = 0.f;
        #pragma unroll
        for (int u = 0; u < 21; ++u) {
            float4 hv = hr[u], pv = pr[u];
            float dx = hv.x - pv.x, dy = hv.y - pv.y;
            float dz = hv.z - pv.z, dw = hv.w - pv.w;
            a += dx * dx + dy * dy + dz * dz + dw * dw;
        }
        out[(size_t)blockIdx.x * 160 + tid] = a;
    }
}

extern "C" void kernel_launch(void* const* d_in, const int* in_sizes, int n_in,
                              void* d_out, int out_size, void* d_ws, size_t ws_size,
                              hipStream_t stream) {
    (void)n_in; (void)out_size; (void)ws_size;
    const float* x     = (const float*)d_in[0];
    const float* c1_w  = (const float*)d_in[1];
    const float* c1_b  = (const float*)d_in[2];
    const float* s2_w  = (const float*)d_in[3];
    const float* s2_b  = (const float*)d_in[4];
    const float* c3_w  = (const float*)d_in[5];
    const float* c3_b  = (const float*)d_in[6];
    const float* s4_w  = (const float*)d_in[7];
    const float* s4_b  = (const float*)d_in[8];
    const float* c5_w  = (const float*)d_in[9];
    const float* c5_b  = (const float*)d_in[10];
    const float* f6_w  = (const float*)d_in[11];
    const float* f6_b  = (const float*)d_in[12];
    const float* rbf_w = (const float*)d_in[13];
    float* out = (float*)d_out;
    float* ws  = (float*)d_ws;

    const int B = in_sizes[0] / 1024;   // 8192

    prep_kernel<<<256, 256, 0, stream>>>(c1_w, c1_b, s2_w, s2_b, c3_w, c3_b,
                                         s4_w, s4_b, c5_w, f6_w, rbf_w, ws);
    lenet_kernel<<<B / 4, 256, 0, stream>>>(x, c5_b, f6_b, ws, out);
}

// Round 2
// 138.171 us; speedup vs baseline: 1.0554x; 1.0430x over previous
//
#include <hip/hip_runtime.h>
#include <math.h>

// LeNet-5 fused forward, G=4 images per 256-thread block, 2048 blocks, f16 MFMA + fdot2.
// Round 13: LDS cut 26.3KB -> 19.6KB so 8 blocks/CU fit (grid = exactly 8/CU -> no tail):
//   - XPADH staged in 2 halves (2 imgs each, half 2 pre-loaded into regs), pitch 40->36
//   - C5 K-packed 512->416: A5 [16][424] fits dead-S2H region; W5H -> [13][128][32]
//   - consts trimmed; S4/A6 overlay dead XPAD region
//   - phase B lane mapping py=tid&15 (2-way-free XPAD bank pattern)
typedef _Float16 h16;
typedef h16  h8v __attribute__((ext_vector_type(8)));
typedef h16  h4v __attribute__((ext_vector_type(4)));
typedef h16  h2v __attribute__((ext_vector_type(2)));
typedef float f4v __attribute__((ext_vector_type(4)));
typedef unsigned int u32;

#if defined(__has_builtin)
#if __has_builtin(__builtin_amdgcn_fdot2)
#define FDOT2(a,b,c) __builtin_amdgcn_fdot2((a),(b),(c),false)
#endif
#endif
#ifndef FDOT2
#define FDOT2(a,b,c) ((c) + (float)(a).x*(float)(b).x + (float)(a).y*(float)(b).y)
#endif

// ws float offsets
#define WS_K1H  0       // 216 h16: folded C1+S2 6x6x6 packed f16 pairs
#define WS_B1   216     // 6 f32
#define WS_B3   224     // 16 f32
#define WS_W3H  240     // [6][16][48] f16 (C3 B^T, k=u*6+v, pad 36..47=0)
#define WS_W5H  2544    // [13][128][32] f16 (C5 B^T, K-packed k=i*25+r*5+c, pads 0) = 53248 h16
#define WS_F6H  29168   // [96][128] f16 (F6 B^T, pads 0)
#define WS_RBFT 35312   // 840 f32: rbf transposed [10][84]

// LDS byte offsets (8 barriers)
#define L_B3    0       // 64B
#define L_C5B   64      // 480B (120 f32)
#define L_F6B   544     // 336B (84 f32)
#define L_S2H   880     // 13824B -> ends 14704 (dead after C)
#define L_A5    880     // 13568B [16][424] h16 (over dead S2H)
#define L_HB    880     // 5632B  [16][88] f32 (over dead A5)
#define L_XPAD  14704   // 5184B: 2 imgs x [36][36] h16 pitch 36 (dead after B)
#define L_S4    14704   // 5376B [4][16][42] h16 (over dead XPAD)
#define L_A6    14704   // 4352B [16][136] h16 (over dead S4)
#define LDS_TOTAL 20080

__device__ const unsigned char MASK16[16] = {7,14,28,56,49,35,15,30,60,57,51,39,27,54,45,63};

// 1.7159*tanh((2/3)x) = 1.7159 - 3.4318/(1 + e^{(4/3)x})
__device__ __forceinline__ float squash(float x) {
    float E = __expf(1.33333333f * x);
    return 1.7159f - 3.4318f * __builtin_amdgcn_rcpf(1.0f + E);
}

__global__ __launch_bounds__(256) void prep_kernel(
    const float* __restrict__ c1_w, const float* __restrict__ c1_b,
    const float* __restrict__ s2_w, const float* __restrict__ s2_b,
    const float* __restrict__ c3_w, const float* __restrict__ c3_b,
    const float* __restrict__ s4_w, const float* __restrict__ s4_b,
    const float* __restrict__ c5_w, const float* __restrict__ f6_w,
    const float* __restrict__ rbf_w,
    float* __restrict__ ws)
{
    const int gid = blockIdx.x * 256 + threadIdx.x;
    const int gstr = gridDim.x * 256;
    h16* K1H = (h16*)ws;
    for (int idx = gid; idx < 216; idx += gstr) {
        int c = idx / 36, r = idx - c * 36;
        int u = r / 6, v = r - u * 6;
        float s = 0.f;
        #pragma unroll
        for (int dy = 0; dy < 2; ++dy)
            #pragma unroll
            for (int dx = 0; dx < 2; ++dx) {
                int ky = u - dy, kx = v - dx;
                if (ky >= 0 && ky < 5 && kx >= 0 && kx < 5)
                    s += c1_w[(c * 5 + ky) * 5 + kx];
            }
        K1H[idx] = (h16)(0.25f * s * s2_w[c]);
    }
    if (gid < 6)  ws[WS_B1 + gid] = s2_w[gid] * c1_b[gid] + s2_b[gid];
    if (gid < 16) ws[WS_B3 + gid] = s4_w[gid] * c3_b[gid] + s4_b[gid];
    h16* W3H = (h16*)(ws + WS_W3H);
    for (int idx = gid; idx < 4608; idx += gstr) {
        int i = idx / 768, r = idx - i * 768;
        int n = r / 48, k = r - n * 48;
        float val = 0.f;
        if (k < 36) {
            int u = k / 6, v = k - u * 6;
            float s = 0.f;
            #pragma unroll
            for (int dy = 0; dy < 2; ++dy)
                #pragma unroll
                for (int dx = 0; dx < 2; ++dx) {
                    int ky = u - dy, kx = v - dx;
                    if (ky >= 0 && ky < 5 && kx >= 0 && kx < 5)
                        s += c3_w[((n * 6 + i) * 5 + ky) * 5 + kx];
                }
            val = ((MASK16[n] >> i) & 1) ? 0.25f * s4_w[n] * s : 0.f;
        }
        W3H[idx] = (h16)val;
    }
    // C5 weights K-packed: [13 kb][128 n][32], kg = kb*32+j = i*25 + (r*5+c) (contiguous in c5_w)
    h16* W5H = (h16*)(ws + WS_W5H);
    for (int idx = gid; idx < 53248; idx += gstr) {
        int kb = idx >> 12, r = idx & 4095;
        int n = r >> 5, k = r & 31;
        int kg = kb * 32 + k;
        float val = (n < 120 && kg < 400) ? c5_w[n * 400 + kg] : 0.f;
        W5H[idx] = (h16)val;
    }
    h16* F6H = (h16*)(ws + WS_F6H);
    for (int idx = gid; idx < 12288; idx += gstr) {
        int n = idx >> 7, k = idx & 127;
        float val = (n < 84 && k < 120) ? f6_w[n * 120 + k] : 0.f;
        F6H[idx] = (h16)val;
    }
    for (int idx = gid; idx < 840; idx += gstr) {
        int k = idx / 10, c = idx - k * 10;
        ws[WS_RBFT + c * 84 + k] = rbf_w[idx];
    }
}

__global__ __launch_bounds__(256, 8) void lenet_kernel(
    const float* __restrict__ x,
    const float* __restrict__ c5_b, const float* __restrict__ f6_b,
    const float* __restrict__ ws,
    float* __restrict__ out)
{
    __shared__ __align__(16) char smem[LDS_TOTAL];
    float* s_b3  = (float*)(smem + L_B3);
    float* s_c5b = (float*)(smem + L_C5B);
    float* s_f6b = (float*)(smem + L_F6B);
    h16*  XPAD   = (h16*)(smem + L_XPAD);
    h16*  S2H    = (h16*)(smem + L_S2H);
    h16*  S4     = (h16*)(smem + L_S4);
    h16*  A5     = (h16*)(smem + L_A5);
    h16*  A6     = (h16*)(smem + L_A6);
    float* HB    = (float*)(smem + L_HB);

    const int tid  = threadIdx.x;
    const int wave = __builtin_amdgcn_readfirstlane(tid >> 6);
    const int lane = tid & 63;
    const int quad = lane >> 4;
    const int lr   = lane & 15;

    // ---- stage consts; stage imgs 0,1 to LDS; issue imgs 2,3 loads into regs ----
    if (tid < 16)  s_b3[tid] = ws[WS_B3 + tid];
    if (tid < 120) s_c5b[tid] = c5_b[tid];
    if (tid < 84)  s_f6b[tid] = f6_b[tid];
    const float* xb = x + (size_t)blockIdx.x * 4096;
    h2v r1[6];
    #pragma unroll
    for (int it = 0; it < 6; ++it) {
        int idx = tid + it * 256;
        if (idx < 1296) {
            int img2 = idx / 648, r2 = idx - img2 * 648;
            int u = r2 / 18, v = r2 - u * 18;
            int sy = min(max(u - 2, 0), 31);
            int c0 = min(max(2 * v - 2, 0), 31);
            int c1 = min(max(2 * v - 1, 0), 31);
            const float* xr0 = xb + img2 * 1024 + sy * 32;
            h2v hv0; hv0.x = (h16)xr0[c0]; hv0.y = (h16)xr0[c1];
            *(h2v*)(XPAD + img2 * 1296 + u * 36 + 2 * v) = hv0;
            const float* xr1 = xr0 + 2048;   // imgs 2,3
            h2v hv1; hv1.x = (h16)xr1[c0]; hv1.y = (h16)xr1[c1];
            r1[it] = hv1;
        }
    }
    __syncthreads();   // [1] XPAD(0,1) + consts ready

    // ======== B: C1+S2+act via fdot2 -> S2H f16 (stage 0: imgs 0,1) ========
    {
        int py = tid & 15, px = tid >> 4;
        const h2v* K1H = (const h2v*)ws;  // [6][18], lane-uniform -> SGPRs
        #pragma unroll 1
        for (int img2 = 0; img2 < 2; ++img2) {
            const h16* basep = XPAD + img2 * 1296 + (2 * py) * 36 + 2 * px;
            h2v win2[18];
            #pragma unroll
            for (int u = 0; u < 6; ++u)
                #pragma unroll
                for (int p = 0; p < 3; ++p)
                    win2[u * 3 + p] = *(const h2v*)(basep + u * 36 + 2 * p);
            #pragma unroll
            for (int c = 0; c < 6; ++c) {
                float acc = ws[WS_B1 + c];
                #pragma unroll
                for (int j = 0; j < 18; ++j)
                    acc = FDOT2(win2[j], K1H[c * 18 + j], acc);
                S2H[img2 * 1728 + c * 288 + py * 18 + px] = (h16)squash(acc);
            }
        }
    }
    __syncthreads();   // [2] XPAD(0,1) reads done

    // ---- write imgs 2,3 from regs ----
    #pragma unroll
    for (int it = 0; it < 6; ++it) {
        int idx = tid + it * 256;
        if (idx < 1296) {
            int img2 = idx / 648, r2 = idx - img2 * 648;
            int u = r2 / 18, v = r2 - u * 18;
            *(h2v*)(XPAD + img2 * 1296 + u * 36 + 2 * v) = r1[it];
        }
    }
    __syncthreads();   // [3] XPAD(2,3) ready

    // ======== B: stage 1 (imgs 2,3) ========
    {
        int py = tid & 15, px = tid >> 4;
        const h2v* K1H = (const h2v*)ws;
        #pragma unroll 1
        for (int img2 = 0; img2 < 2; ++img2) {
            const h16* basep = XPAD + img2 * 1296 + (2 * py) * 36 + 2 * px;
            h2v win2[18];
            #pragma unroll
            for (int u = 0; u < 6; ++u)
                #pragma unroll
                for (int p = 0; p < 3; ++p)
                    win2[u * 3 + p] = *(const h2v*)(basep + u * 36 + 2 * p);
            #pragma unroll
            for (int c = 0; c < 6; ++c) {
                float acc = ws[WS_B1 + c];
                #pragma unroll
                for (int j = 0; j < 18; ++j)
                    acc = FDOT2(win2[j], K1H[c * 18 + j], acc);
                S2H[(2 + img2) * 1728 + c * 288 + py * 18 + px] = (h16)squash(acc);
            }
        }
    }
    __syncthreads();   // [4] S2H ready; XPAD dead

    // ======== C: C3+S4 via MFMA, A-fragments direct from S2H ========
    {
        const h16* W3H = (const h16*)(ws + WS_W3H);
        int o0, o1, o2, o3;
        {
            int k0 = 8 * quad;
            int u0 = k0 / 6, v0 = k0 - u0 * 6;  o0 = u0 * 18 + v0;
            int k1 = k0 + 2;
            int u1 = k1 / 6, v1 = k1 - u1 * 6;  o1 = u1 * 18 + v1;
            int k2 = k0 + 4;
            int u2 = k2 / 6, v2 = k2 - u2 * 6;  o2 = u2 * 18 + v2;
            int k3 = k0 + 6;
            int u3 = k3 / 6, v3 = k3 - u3 * 6;  o3 = u3 * 18 + v3;
        }
        int baseh0, baseh1, baseh2;
        {
            int m0 = wave * 16 + lr;
            int i0 = m0 / 36, p0 = m0 - i0 * 36;
            baseh0 = i0 * 1728 + (2 * (p0 / 6)) * 18 + 2 * (p0 % 6);
            int m1 = (wave + 4) * 16 + lr;
            int i1 = m1 / 36, p1 = m1 - i1 * 36;
            baseh1 = i1 * 1728 + (2 * (p1 / 6)) * 18 + 2 * (p1 % 6);
            int m2 = 128 + lr;   // Mt=8 (wave 0 only)
            int i2 = m2 / 36, p2 = m2 - i2 * 36;
            baseh2 = i2 * 1728 + (2 * (p2 / 6)) * 18 + 2 * (p2 % 6);
        }
        f4v cacc0 = {}, cacc1 = {}, cacc2 = {};
        const bool w0 = (wave == 0);
        #pragma unroll
        for (int i = 0; i < 6; ++i) {
            const h16* bbase = W3H + i * 768 + lr * 48;
            h8v w3a = *(const h8v*)(bbase + quad * 8);
            h4v w3b = *(const h4v*)(bbase + 32 + quad * 4);
            const h16* bp0 = S2H + baseh0 + i * 288;
            {
                union { u32 u[4]; h8v h; } av;
                av.u[0] = *(const u32*)(bp0 + o0);
                av.u[1] = *(const u32*)(bp0 + o1);
                av.u[2] = *(const u32*)(bp0 + o2);
                av.u[3] = *(const u32*)(bp0 + o3);
                cacc0 = __builtin_amdgcn_mfma_f32_16x16x32_f16(av.h, w3a, cacc0, 0, 0, 0);
                union { u32 u[2]; h4v h; } av2;
                av2.u[0] = *(const u32*)(bp0 + 92);
                av2.u[1] = *(const u32*)(bp0 + 94);
                cacc0 = __builtin_amdgcn_mfma_f32_16x16x16f16(av2.h, w3b, cacc0, 0, 0, 0);
            }
            const h16* bp1 = S2H + baseh1 + i * 288;
            {
                union { u32 u[4]; h8v h; } av;
                av.u[0] = *(const u32*)(bp1 + o0);
                av.u[1] = *(const u32*)(bp1 + o1);
                av.u[2] = *(const u32*)(bp1 + o2);
                av.u[3] = *(const u32*)(bp1 + o3);
                cacc1 = __builtin_amdgcn_mfma_f32_16x16x32_f16(av.h, w3a, cacc1, 0, 0, 0);
                union { u32 u[2]; h4v h; } av2;
                av2.u[0] = *(const u32*)(bp1 + 92);
                av2.u[1] = *(const u32*)(bp1 + 94);
                cacc1 = __builtin_amdgcn_mfma_f32_16x16x16f16(av2.h, w3b, cacc1, 0, 0, 0);
            }
            if (w0) {
                const h16* bp2 = S2H + baseh2 + i * 288;
                union { u32 u[4]; h8v h; } av;
                av.u[0] = *(const u32*)(bp2 + o0);
                av.u[1] = *(const u32*)(bp2 + o1);
                av.u[2] = *(const u32*)(bp2 + o2);
                av.u[3] = *(const u32*)(bp2 + o3);
                cacc2 = __builtin_amdgcn_mfma_f32_16x16x32_f16(av.h, w3a, cacc2, 0, 0, 0);
                union { u32 u[2]; h4v h; } av2;
                av2.u[0] = *(const u32*)(bp2 + 92);
                av2.u[1] = *(const u32*)(bp2 + 94);
                cacc2 = __builtin_amdgcn_mfma_f32_16x16x16f16(av2.h, w3b, cacc2, 0, 0, 0);
            }
        }
        // epilogue: squash -> S4 (over dead XPAD)
        float b3v = s_b3[lr];
        {
            #pragma unroll
            for (int r = 0; r < 4; ++r) {
                int m = wave * 16 + quad * 4 + r;
                int img = m / 36, pos = m - img * 36;
                S4[img * 672 + lr * 42 + pos] = (h16)squash(cacc0[r] + b3v);
            }
            #pragma unroll
            for (int r = 0; r < 4; ++r) {
                int m = (wave + 4) * 16 + quad * 4 + r;
                int img = m / 36, pos = m - img * 36;
                S4[img * 672 + lr * 42 + pos] = (h16)squash(cacc1[r] + b3v);
            }
            if (w0) {
                #pragma unroll
                for (int r = 0; r < 4; ++r) {
                    int m = 128 + quad * 4 + r;
                    int img = m / 36, pos = m - img * 36;
                    S4[img * 672 + lr * 42 + pos] = (h16)squash(cacc2[r] + b3v);
                }
            }
        }
    }
    __syncthreads();   // [5] S4 ready; all S2H reads done

    // ======== D: C5 via MFMA. GEMM [16 x 416] x [416 x 128], K-packed ========
    {
        // build A5 [16][424] (over dead S2H): thread = (m, i); A5[m][i*25+k] = window val
        {
            int m = tid >> 4, i = tid & 15;
            int img = m >> 2, q = m & 3, qy = q >> 1, qx = q & 1;
            const h16* s4b = S4 + img * 672 + i * 42 + qy * 6 + qx;
            h16* dst = A5 + m * 424 + i * 25;
            #pragma unroll
            for (int k = 0; k < 25; ++k)
                dst[k] = s4b[(k / 5) * 6 + (k % 5)];
            if (i == 15) {
                #pragma unroll
                for (int j = 0; j < 12; ++j)
                    *(u32*)(A5 + m * 424 + 400 + 2 * j) = 0u;
            }
        }
        __syncthreads();   // [6] A5 ready
        const h16* W5H = (const h16*)(ws + WS_W5H);
        f4v dacc0 = {}, dacc1 = {};
        #pragma unroll
        for (int i = 0; i < 13; ++i) {
            h8v bf0 = *(const h8v*)(W5H + i * 4096 + (wave * 32 + lr) * 32 + quad * 8);
            h8v bf1 = *(const h8v*)(W5H + i * 4096 + (wave * 32 + 16 + lr) * 32 + quad * 8);
            h8v af0 = *(const h8v*)(A5 + lr * 424 + i * 32 + quad * 8);
            dacc0 = __builtin_amdgcn_mfma_f32_16x16x32_f16(af0, bf0, dacc0, 0, 0, 0);
            dacc1 = __builtin_amdgcn_mfma_f32_16x16x32_f16(af0, bf1, dacc1, 0, 0, 0);
        }
        // zero pad cols 120..127 of A6 (over dead S4)
        if (tid < 64) {
            int m = tid >> 2, j = tid & 3;
            *(u32*)(A6 + m * 136 + 120 + 2 * j) = 0u;
        }
        // epilogue, reference reshape: row=img*4+(n/30), col=(n%30)*4+q
        {
            int n0 = wave * 32 + lr;
            if (n0 < 120) {
                int tt = n0 / 30, cb = (n0 - tt * 30) * 4;
                float bias = s_c5b[n0];
                #pragma unroll
                for (int r = 0; r < 4; ++r) {
                    int m = quad * 4 + r;
                    A6[((m >> 2) * 4 + tt) * 136 + cb + (m & 3)] = (h16)(dacc0[r] + bias);
                }
            }
            int n1 = wave * 32 + 16 + lr;
            if (n1 < 120) {
                int tt = n1 / 30, cb = (n1 - tt * 30) * 4;
                float bias = s_c5b[n1];
                #pragma unroll
                for (int r = 0; r < 4; ++r) {
                    int m = quad * 4 + r;
                    A6[((m >> 2) * 4 + tt) * 136 + cb + (m & 3)] = (h16)(dacc1[r] + bias);
                }
            }
        }
    }
    __syncthreads();   // [7] A6 ready; all A5 reads done

    // ======== E: F6+act via MFMA. GEMM [16 x 128] x [128 x 96] ========
    {
        const h16* F6H = (const h16*)(ws + WS_F6H);
        f4v eacc0 = {}, eacc1 = {};
        const bool w2 = (wave < 2);
        #pragma unroll
        for (int kc = 0; kc < 4; ++kc) {
            h8v a8 = *(const h8v*)(A6 + lr * 136 + kc * 32 + quad * 8);
            h8v b0 = *(const h8v*)(F6H + (wave * 16 + lr) * 128 + kc * 32 + quad * 8);
            eacc0 = __builtin_amdgcn_mfma_f32_16x16x32_f16(a8, b0, eacc0, 0, 0, 0);
            if (w2) {
                h8v b1 = *(const h8v*)(F6H + ((wave + 4) * 16 + lr) * 128 + kc * 32 + quad * 8);
                eacc1 = __builtin_amdgcn_mfma_f32_16x16x32_f16(a8, b1, eacc1, 0, 0, 0);
            }
        }
        {
            int n = wave * 16 + lr;   // 0..63 < 84
            float bias = s_f6b[n];
            #pragma unroll
            for (int r = 0; r < 4; ++r) {
                int m = quad * 4 + r;
                HB[m * 88 + n] = squash(eacc0[r] + bias);   // HB over dead A5
            }
        }
        if (w2) {
            int n = (wave + 4) * 16 + lr;  // 64..95
            if (n < 84) {
                float bias = s_f6b[n];
                #pragma unroll
                for (int r = 0; r < 4; ++r) {
                    int m = quad * 4 + r;
                    HB[m * 88 + n] = squash(eacc1[r] + bias);
                }
            }
        }
    }
    __syncthreads();   // [8] HB ready

    // ======== F: RBF distances (VALU); prototypes from L2-resident rbfT ========
    if (tid < 160) {
        int m = tid / 10, cls = tid - m * 10;
        const float4* hr = (const float4*)(HB + m * 88);
        const float4* pr = (const float4*)(ws + WS_RBFT + cls * 84);
        float a = 0.f;
        #pragma unroll
        for (int u = 0; u < 21; ++u) {
            float4 hv = hr[u], pv = pr[u];
            float dx = hv.x - pv.x, dy = hv.y - pv.y;
            float dz = hv.z - pv.z, dw = hv.w - pv.w;
            a += dx * dx + dy * dy + dz * dz + dw * dw;
        }
        out[(size_t)blockIdx.x * 160 + tid] = a;
    }
}

extern "C" void kernel_launch(void* const* d_in, const int* in_sizes, int n_in,
                              void* d_out, int out_size, void* d_ws, size_t ws_size,
                              hipStream_t stream) {
    (void)n_in; (void)out_size; (void)ws_size;
    const float* x     = (const float*)d_in[0];
    const float* c1_w  = (const float*)d_in[1];
    const float* c1_b  = (const float*)d_in[2];
    const float* s2_w  = (const float*)d_in[3];
    const float* s2_b  = (const float*)d_in[4];
    const float* c3_w  = (const float*)d_in[5];
    const float* c3_b  = (const float*)d_in[6];
    const float* s4_w  = (const float*)d_in[7];
    const float* s4_b  = (const float*)d_in[8];
    const float* c5_w  = (const float*)d_in[9];
    const float* c5_b  = (const float*)d_in[10];
    const float* f6_w  = (const float*)d_in[11];
    const float* f6_b  = (const float*)d_in[12];
    const float* rbf_w = (const float*)d_in[13];
    float* out = (float*)d_out;
    float* ws  = (float*)d_ws;

    const int B = in_sizes[0] / 1024;   // 8192

    prep_kernel<<<256, 256, 0, stream>>>(c1_w, c1_b, s2_w, s2_b, c3_w, c3_b,
                                         s4_w, s4_b, c5_w, f6_w, rbf_w, ws);
    lenet_kernel<<<B / 4, 256, 0, stream>>>(x, c5_b, f6_b, ws, out);
}

// Round 4
// 135.143 us; speedup vs baseline: 1.0791x; 1.0224x over previous
//
#include <hip/hip_runtime.h>
#include <math.h>

// LeNet-5 fused forward, G=4 images per 256-thread block, 2048 blocks, all-MFMA.
// Round 15: fix round-14 halo staging bug (544 halo cells need 3 x 256-thread passes,
// loop only did 2 -> 32 uninitialized LDS cells -> NaN). Structure otherwise unchanged:
//   - phase B (C1+S2) as MFMA im2col GEMM [1024 x 36] x [36 x 6], B-matrix in 6 VGPRs
//   - phase A: coalesced float4 loads + packed h2v stores; halo separate
//   - phase D: A5 K-packed pitch 26 (aligned b32 stores)
//   - bias folded into MFMA accumulator init in phases B/C/D/E
typedef _Float16 h16;
typedef h16  h8v __attribute__((ext_vector_type(8)));
typedef h16  h4v __attribute__((ext_vector_type(4)));
typedef h16  h2v __attribute__((ext_vector_type(2)));
typedef float f4v __attribute__((ext_vector_type(4)));
typedef unsigned int u32;

// ws float offsets
#define WS_B1   0       // 6 f32
#define WS_B3   8       // 16 f32
#define WS_KB1  24      // [16][48] f16 (C1 B^T, k=u*6+v, rows>=6 and k>=36 zero) = 768 h16
#define WS_W3H  408     // [6][16][48] f16 (C3 B^T, k=u*6+v, pad 36..47=0) = 4608 h16
#define WS_W5H  2712    // [13][128][32] f16 (C5 B^T, K-packed kg=i*26+r, r<25 valid) = 53248 h16
#define WS_F6H  29336   // [96][128] f16 (F6 B^T, pads 0) = 12288 h16
#define WS_RBFT 35480   // 840 f32: rbf transposed [10][84]

// LDS byte offsets (8 barriers)
#define L_B3    0       // 64B
#define L_C5B   64      // 480B (120 f32)
#define L_F6B   544     // 336B (84 f32)
#define L_S2H   880     // 13824B [4][6][16][18] h16 (dead after C)
#define L_A5    880     // 13568B [16][424] h16 (over dead S2H)
#define L_HB    880     // 5632B  [16][88] f32 (over dead A5)
#define L_XPAD  14704   // 5184B: 2 imgs x [36][36] h16 (dead after B)
#define L_S4    14704   // 5376B [4][16][42] h16 (over dead XPAD)
#define L_A6    14704   // 4352B [16][136] h16 (over dead S4)
#define LDS_TOTAL 20080

__device__ const unsigned char MASK16[16] = {7,14,28,56,49,35,15,30,60,57,51,39,27,54,45,63};

// 1.7159*tanh((2/3)x) = 1.7159 - 3.4318/(1 + e^{(4/3)x})
__device__ __forceinline__ float squash(float x) {
    float E = __expf(1.33333333f * x);
    return 1.7159f - 3.4318f * __builtin_amdgcn_rcpf(1.0f + E);
}

__global__ __launch_bounds__(256) void prep_kernel(
    const float* __restrict__ c1_w, const float* __restrict__ c1_b,
    const float* __restrict__ s2_w, const float* __restrict__ s2_b,
    const float* __restrict__ c3_w, const float* __restrict__ c3_b,
    const float* __restrict__ s4_w, const float* __restrict__ s4_b,
    const float* __restrict__ c5_w, const float* __restrict__ f6_w,
    const float* __restrict__ rbf_w,
    float* __restrict__ ws)
{
    const int gid = blockIdx.x * 256 + threadIdx.x;
    const int gstr = gridDim.x * 256;
    if (gid < 6)  ws[WS_B1 + gid] = s2_w[gid] * c1_b[gid] + s2_b[gid];
    if (gid < 16) ws[WS_B3 + gid] = s4_w[gid] * c3_b[gid] + s4_b[gid];
    // KB1: [16 n][48 k] B^T for C1+S2 folded conv; n>=6 or k>=36 -> 0
    h16* KB1 = (h16*)(ws + WS_KB1);
    for (int idx = gid; idx < 768; idx += gstr) {
        int n = idx / 48, k = idx - n * 48;
        float val = 0.f;
        if (n < 6 && k < 36) {
            int u = k / 6, v = k - u * 6;
            float s = 0.f;
            #pragma unroll
            for (int dy = 0; dy < 2; ++dy)
                #pragma unroll
                for (int dx = 0; dx < 2; ++dx) {
                    int ky = u - dy, kx = v - dx;
                    if (ky >= 0 && ky < 5 && kx >= 0 && kx < 5)
                        s += c1_w[(n * 5 + ky) * 5 + kx];
                }
            val = 0.25f * s * s2_w[n];
        }
        KB1[idx] = (h16)val;
    }
    h16* W3H = (h16*)(ws + WS_W3H);
    for (int idx = gid; idx < 4608; idx += gstr) {
        int i = idx / 768, r = idx - i * 768;
        int n = r / 48, k = r - n * 48;
        float val = 0.f;
        if (k < 36) {
            int u = k / 6, v = k - u * 6;
            float s = 0.f;
            #pragma unroll
            for (int dy = 0; dy < 2; ++dy)
                #pragma unroll
                for (int dx = 0; dx < 2; ++dx) {
                    int ky = u - dy, kx = v - dx;
                    if (ky >= 0 && ky < 5 && kx >= 0 && kx < 5)
                        s += c3_w[((n * 6 + i) * 5 + ky) * 5 + kx];
                }
            val = ((MASK16[n] >> i) & 1) ? 0.25f * s4_w[n] * s : 0.f;
        }
        W3H[idx] = (h16)val;
    }
    // C5 weights K-packed pitch 26: kg = kb*32+k; i = kg/26, r = kg%26; r<25 valid
    h16* W5H = (h16*)(ws + WS_W5H);
    for (int idx = gid; idx < 53248; idx += gstr) {
        int kb = idx >> 12, rr = idx & 4095;
        int n = rr >> 5, k = rr & 31;
        int kg = kb * 32 + k;
        int i = kg / 26, r = kg - i * 26;
        float val = (n < 120 && r < 25) ? c5_w[n * 400 + i * 25 + r] : 0.f;
        W5H[idx] = (h16)val;
    }
    h16* F6H = (h16*)(ws + WS_F6H);
    for (int idx = gid; idx < 12288; idx += gstr) {
        int n = idx >> 7, k = idx & 127;
        float val = (n < 84 && k < 120) ? f6_w[n * 120 + k] : 0.f;
        F6H[idx] = (h16)val;
    }
    for (int idx = gid; idx < 840; idx += gstr) {
        int k = idx / 10, c = idx - k * 10;
        ws[WS_RBFT + c * 84 + k] = rbf_w[idx];
    }
}

__global__ __launch_bounds__(256, 8) void lenet_kernel(
    const float* __restrict__ x,
    const float* __restrict__ c5_b, const float* __restrict__ f6_b,
    const float* __restrict__ ws,
    float* __restrict__ out)
{
    __shared__ __align__(16) char smem[LDS_TOTAL];
    float* s_b3  = (float*)(smem + L_B3);
    float* s_c5b = (float*)(smem + L_C5B);
    float* s_f6b = (float*)(smem + L_F6B);
    h16*  XPAD   = (h16*)(smem + L_XPAD);
    h16*  S2H    = (h16*)(smem + L_S2H);
    h16*  S4     = (h16*)(smem + L_S4);
    h16*  A5     = (h16*)(smem + L_A5);
    h16*  A6     = (h16*)(smem + L_A6);
    float* HB    = (float*)(smem + L_HB);

    const int tid  = threadIdx.x;
    const int wave = __builtin_amdgcn_readfirstlane(tid >> 6);
    const int lane = tid & 63;
    const int quad = lane >> 4;
    const int lr   = lane & 15;

    // ---- stage consts; load B-frags for phase B once (6 VGPRs) ----
    if (tid < 16)  s_b3[tid] = ws[WS_B3 + tid];
    if (tid < 120) s_c5b[tid] = c5_b[tid];
    if (tid < 84)  s_f6b[tid] = f6_b[tid];
    const float* xb = x + (size_t)blockIdx.x * 4096;
    const h16* KB1 = (const h16*)(ws + WS_KB1);
    h8v w1a = *(const h8v*)(KB1 + lr * 48 + quad * 8);
    h4v w1b = *(const h4v*)(KB1 + lr * 48 + 32 + quad * 4);
    float b1v = ws[WS_B1 + (lr < 6 ? lr : 0)];
    // per-quad im2col k-offsets (XPAD pitch 36): k=8q+2j -> (k/6)*36 + k%6
    int oB0, oB1, oB2, oB3;
    {
        int k0 = 8 * quad;      oB0 = (k0 / 6) * 36 + (k0 % 6);
        int k1 = 8 * quad + 2;  oB1 = (k1 / 6) * 36 + (k1 % 6);
        int k2 = 8 * quad + 4;  oB2 = (k2 / 6) * 36 + (k2 % 6);
        int k3 = 8 * quad + 6;  oB3 = (k3 / 6) * 36 + (k3 % 6);
    }

    // phase A stage: load imgs (2s, 2s+1) into XPAD with replicate pad
    auto stageA = [&](int s) {
        #pragma unroll
        for (int k = 0; k < 2; ++k) {
            int idx = tid + k * 256;            // 0..511: interior 2x32x8 float4
            int im = idx >> 8;
            int r  = (idx >> 3) & 31;
            int c4 = idx & 7;
            float4 v = *(const float4*)(xb + (2 * s + im) * 1024 + r * 32 + c4 * 4);
            h2v p0; p0.x = (h16)v.x; p0.y = (h16)v.y;
            h2v p1; p1.x = (h16)v.z; p1.y = (h16)v.w;
            h16* d = XPAD + im * 1296 + (r + 2) * 36 + (4 * c4 + 2);
            *(h2v*)(d)     = p0;
            *(h2v*)(d + 2) = p1;
        }
        #pragma unroll
        for (int k = 0; k < 3; ++k) {
            int e = tid + k * 256;              // 544 halo cells (3 passes!)
            if (e < 544) {
                int im = (e >= 272) ? 1 : 0;
                int h = e - 272 * im;
                int u, v;
                if (h < 144) { int q = h / 36; u = (q < 2) ? q : 32 + q; v = h - q * 36; }
                else { int g = h - 144; u = 2 + (g >> 2); int q = g & 3; v = (q < 2) ? q : 32 + q; }
                int sr = min(max(u - 2, 0), 31), sc = min(max(v - 2, 0), 31);
                XPAD[im * 1296 + u * 36 + v] = (h16)xb[(2 * s + im) * 1024 + sr * 32 + sc];
            }
        }
    };

    // phase B stage: C1+S2+act via MFMA im2col; wave -> (img = wave>>1, py-half = wave&1)
    auto stageB = [&](int s) {
        const h16* bp = XPAD + (wave >> 1) * 1296 + (wave & 1) * 576 + 2 * lr;
        h16* s2base = S2H + (s * 2 + (wave >> 1)) * 1728 + lr * 288 + (wave & 1) * 144 + quad * 4;
        #pragma unroll
        for (int tt = 0; tt < 8; ++tt) {
            union { u32 u[4]; h8v h; } av;
            av.u[0] = *(const u32*)(bp + oB0);
            av.u[1] = *(const u32*)(bp + oB1);
            av.u[2] = *(const u32*)(bp + oB2);
            av.u[3] = *(const u32*)(bp + oB3);
            f4v acc = {b1v, b1v, b1v, b1v};
            acc = __builtin_amdgcn_mfma_f32_16x16x32_f16(av.h, w1a, acc, 0, 0, 0);
            union { u32 u[2]; h4v h; } av2;
            av2.u[0] = *(const u32*)(bp + 182);   // k=32,33 (u=5,v=2,3)
            av2.u[1] = *(const u32*)(bp + 184);   // k=34,35
            acc = __builtin_amdgcn_mfma_f32_16x16x16f16(av2.h, w1b, acc, 0, 0, 0);
            if (lr < 6) {
                h2v q0; q0.x = (h16)squash(acc[0]); q0.y = (h16)squash(acc[1]);
                h2v q1; q1.x = (h16)squash(acc[2]); q1.y = (h16)squash(acc[3]);
                *(h2v*)(s2base + tt * 18)     = q0;
                *(h2v*)(s2base + tt * 18 + 2) = q1;
            }
            bp += 72;
        }
    };

    stageA(0);
    __syncthreads();   // [1] XPAD(0,1) + consts ready
    stageB(0);
    __syncthreads();   // [2] XPAD(0,1) reads done
    stageA(1);
    __syncthreads();   // [3] XPAD(2,3) ready
    stageB(1);
    __syncthreads();   // [4] S2H ready; XPAD dead

    // ======== C: C3+S4 via MFMA, A-fragments direct from S2H ========
    {
        const h16* W3H = (const h16*)(ws + WS_W3H);
        int o0, o1, o2, o3;
        {
            int k0 = 8 * quad;
            int u0 = k0 / 6, v0 = k0 - u0 * 6;  o0 = u0 * 18 + v0;
            int k1 = k0 + 2;
            int u1 = k1 / 6, v1 = k1 - u1 * 6;  o1 = u1 * 18 + v1;
            int k2 = k0 + 4;
            int u2 = k2 / 6, v2 = k2 - u2 * 6;  o2 = u2 * 18 + v2;
            int k3 = k0 + 6;
            int u3 = k3 / 6, v3 = k3 - u3 * 6;  o3 = u3 * 18 + v3;
        }
        int baseh0, baseh1, baseh2;
        {
            int m0 = wave * 16 + lr;
            int i0 = m0 / 36, p0 = m0 - i0 * 36;
            baseh0 = i0 * 1728 + (2 * (p0 / 6)) * 18 + 2 * (p0 % 6);
            int m1 = (wave + 4) * 16 + lr;
            int i1 = m1 / 36, p1 = m1 - i1 * 36;
            baseh1 = i1 * 1728 + (2 * (p1 / 6)) * 18 + 2 * (p1 % 6);
            int m2 = 128 + lr;   // Mt=8 (wave 0 only)
            int i2 = m2 / 36, p2 = m2 - i2 * 36;
            baseh2 = i2 * 1728 + (2 * (p2 / 6)) * 18 + 2 * (p2 % 6);
        }
        float b3v = s_b3[lr];
        f4v cinit = {b3v, b3v, b3v, b3v};
        f4v cacc0 = cinit, cacc1 = cinit, cacc2 = cinit;
        const bool w0 = (wave == 0);
        #pragma unroll
        for (int i = 0; i < 6; ++i) {
            const h16* bbase = W3H + i * 768 + lr * 48;
            h8v w3a = *(const h8v*)(bbase + quad * 8);
            h4v w3b = *(const h4v*)(bbase + 32 + quad * 4);
            const h16* bp0 = S2H + baseh0 + i * 288;
            {
                union { u32 u[4]; h8v h; } av;
                av.u[0] = *(const u32*)(bp0 + o0);
                av.u[1] = *(const u32*)(bp0 + o1);
                av.u[2] = *(const u32*)(bp0 + o2);
                av.u[3] = *(const u32*)(bp0 + o3);
                cacc0 = __builtin_amdgcn_mfma_f32_16x16x32_f16(av.h, w3a, cacc0, 0, 0, 0);
                union { u32 u[2]; h4v h; } av2;
                av2.u[0] = *(const u32*)(bp0 + 92);
                av2.u[1] = *(const u32*)(bp0 + 94);
                cacc0 = __builtin_amdgcn_mfma_f32_16x16x16f16(av2.h, w3b, cacc0, 0, 0, 0);
            }
            const h16* bp1 = S2H + baseh1 + i * 288;
            {
                union { u32 u[4]; h8v h; } av;
                av.u[0] = *(const u32*)(bp1 + o0);
                av.u[1] = *(const u32*)(bp1 + o1);
                av.u[2] = *(const u32*)(bp1 + o2);
                av.u[3] = *(const u32*)(bp1 + o3);
                cacc1 = __builtin_amdgcn_mfma_f32_16x16x32_f16(av.h, w3a, cacc1, 0, 0, 0);
                union { u32 u[2]; h4v h; } av2;
                av2.u[0] = *(const u32*)(bp1 + 92);
                av2.u[1] = *(const u32*)(bp1 + 94);
                cacc1 = __builtin_amdgcn_mfma_f32_16x16x16f16(av2.h, w3b, cacc1, 0, 0, 0);
            }
            if (w0) {
                const h16* bp2 = S2H + baseh2 + i * 288;
                union { u32 u[4]; h8v h; } av;
                av.u[0] = *(const u32*)(bp2 + o0);
                av.u[1] = *(const u32*)(bp2 + o1);
                av.u[2] = *(const u32*)(bp2 + o2);
                av.u[3] = *(const u32*)(bp2 + o3);
                cacc2 = __builtin_amdgcn_mfma_f32_16x16x32_f16(av.h, w3a, cacc2, 0, 0, 0);
                union { u32 u[2]; h4v h; } av2;
                av2.u[0] = *(const u32*)(bp2 + 92);
                av2.u[1] = *(const u32*)(bp2 + 94);
                cacc2 = __builtin_amdgcn_mfma_f32_16x16x16f16(av2.h, w3b, cacc2, 0, 0, 0);
            }
        }
        // epilogue: squash -> S4 (over dead XPAD)
        {
            #pragma unroll
            for (int r = 0; r < 4; ++r) {
                int m = wave * 16 + quad * 4 + r;
                int img = m / 36, pos = m - img * 36;
                S4[img * 672 + lr * 42 + pos] = (h16)squash(cacc0[r]);
            }
            #pragma unroll
            for (int r = 0; r < 4; ++r) {
                int m = (wave + 4) * 16 + quad * 4 + r;
                int img = m / 36, pos = m - img * 36;
                S4[img * 672 + lr * 42 + pos] = (h16)squash(cacc1[r]);
            }
            if (w0) {
                #pragma unroll
                for (int r = 0; r < 4; ++r) {
                    int m = 128 + quad * 4 + r;
                    int img = m / 36, pos = m - img * 36;
                    S4[img * 672 + lr * 42 + pos] = (h16)squash(cacc2[r]);
                }
            }
        }
    }
    __syncthreads();   // [5] S4 ready; all S2H reads done

    // ======== D: C5 via MFMA. GEMM [16 x 416] x [416 x 128], K-packed pitch 26 ========
    {
        // build A5 [16][424] (over dead S2H): thread = (m, i); A5[m][i*26+k] = window val
        {
            int m = tid >> 4, i = tid & 15;
            int img = m >> 2, q = m & 3, qy = q >> 1, qx = q & 1;
            const h16* s4b = S4 + img * 672 + i * 42 + qy * 6 + qx;
            u32* dst = (u32*)(A5 + m * 424 + i * 26);
            #pragma unroll
            for (int w = 0; w < 12; ++w) {
                int k0 = 2 * w, k1 = 2 * w + 1;
                union { h2v h; u32 u; } p;
                p.h.x = s4b[(k0 / 5) * 6 + (k0 % 5)];
                p.h.y = s4b[(k1 / 5) * 6 + (k1 % 5)];
                dst[w] = p.u;
            }
            {
                union { h2v h; u32 u; } p;
                p.h.x = s4b[28];  // k=24 -> (4,4)
                p.h.y = (h16)0.f;
                dst[12] = p.u;
            }
        }
        __syncthreads();   // [6] A5 ready
        const h16* W5H = (const h16*)(ws + WS_W5H);
        float c5b0 = s_c5b[wave * 32 + lr];
        float c5b1 = s_c5b[wave * 32 + 16 + lr];   // may over-read into F6B consts; discarded
        f4v dacc0 = {c5b0, c5b0, c5b0, c5b0};
        f4v dacc1 = {c5b1, c5b1, c5b1, c5b1};
        #pragma unroll
        for (int i = 0; i < 13; ++i) {
            h8v bf0 = *(const h8v*)(W5H + i * 4096 + (wave * 32 + lr) * 32 + quad * 8);
            h8v bf1 = *(const h8v*)(W5H + i * 4096 + (wave * 32 + 16 + lr) * 32 + quad * 8);
            h8v af0 = *(const h8v*)(A5 + lr * 424 + i * 32 + quad * 8);
            dacc0 = __builtin_amdgcn_mfma_f32_16x16x32_f16(af0, bf0, dacc0, 0, 0, 0);
            dacc1 = __builtin_amdgcn_mfma_f32_16x16x32_f16(af0, bf1, dacc1, 0, 0, 0);
        }
        // zero pad cols 120..127 of A6 (over dead S4)
        if (tid < 64) {
            int m = tid >> 2, j = tid & 3;
            *(u32*)(A6 + m * 136 + 120 + 2 * j) = 0u;
        }
        // epilogue, reference reshape: row=img*4+(n/30), col=(n%30)*4+q
        {
            int n0 = wave * 32 + lr;
            if (n0 < 120) {
                int tt = n0 / 30, cb = (n0 - tt * 30) * 4;
                #pragma unroll
                for (int r = 0; r < 4; ++r) {
                    int m = quad * 4 + r;
                    A6[((m >> 2) * 4 + tt) * 136 + cb + (m & 3)] = (h16)dacc0[r];
                }
            }
            int n1 = wave * 32 + 16 + lr;
            if (n1 < 120) {
                int tt = n1 / 30, cb = (n1 - tt * 30) * 4;
                #pragma unroll
                for (int r = 0; r < 4; ++r) {
                    int m = quad * 4 + r;
                    A6[((m >> 2) * 4 + tt) * 136 + cb + (m & 3)] = (h16)dacc1[r];
                }
            }
        }
    }
    __syncthreads();   // [7] A6 ready; all A5 reads done

    // ======== E: F6+act via MFMA. GEMM [16 x 128] x [128 x 96] ========
    {
        const h16* F6H = (const h16*)(ws + WS_F6H);
        float f60 = s_f6b[wave * 16 + lr];
        f4v eacc0 = {f60, f60, f60, f60};
        f4v eacc1 = {};
        const bool w2 = (wave < 2);
        if (w2) {
            int n1 = (wave + 4) * 16 + lr;
            float f61 = (n1 < 84) ? s_f6b[n1] : 0.f;
            eacc1[0] = f61; eacc1[1] = f61; eacc1[2] = f61; eacc1[3] = f61;
        }
        #pragma unroll
        for (int kc = 0; kc < 4; ++kc) {
            h8v a8 = *(const h8v*)(A6 + lr * 136 + kc * 32 + quad * 8);
            h8v b0 = *(const h8v*)(F6H + (wave * 16 + lr) * 128 + kc * 32 + quad * 8);
            eacc0 = __builtin_amdgcn_mfma_f32_16x16x32_f16(a8, b0, eacc0, 0, 0, 0);
            if (w2) {
                h8v b1 = *(const h8v*)(F6H + ((wave + 4) * 16 + lr) * 128 + kc * 32 + quad * 8);
                eacc1 = __builtin_amdgcn_mfma_f32_16x16x32_f16(a8, b1, eacc1, 0, 0, 0);
            }
        }
        {
            int n = wave * 16 + lr;   // 0..63 < 84
            #pragma unroll
            for (int r = 0; r < 4; ++r) {
                int m = quad * 4 + r;
                HB[m * 88 + n] = squash(eacc0[r]);   // HB over dead A5
            }
        }
        if (w2) {
            int n = (wave + 4) * 16 + lr;  // 64..95
            if (n < 84) {
                #pragma unroll
                for (int r = 0; r < 4; ++r) {
                    int m = quad * 4 + r;
                    HB[m * 88 + n] = squash(eacc1[r]);
                }
            }
        }
    }
    __syncthreads();   // [8] HB ready

    // ======== F: RBF distances (VALU); prototypes from L2-resident rbfT ========
    if (tid < 160) {
        int m = tid / 10, cls = tid - m * 10;
        const float4* hr = (const float4*)(HB + m * 88);
        const float4* pr = (const float4*)(ws + WS_RBFT + cls * 84);
        float a = 0.f;
        #pragma unroll
        for (int u = 0; u < 21; ++u) {
            float4 hv = hr[u], pv = pr[u];
            float dx = hv.x - pv.x, dy = hv.y - pv.y;
            float dz = hv.z - pv.z, dw = hv.w - pv.w;
            a += dx * dx + dy * dy + dz * dz + dw * dw;
        }
        out[(size_t)blockIdx.x * 160 + tid] = a;
    }
}

extern "C" void kernel_launch(void* const* d_in, const int* in_sizes, int n_in,
                              void* d_out, int out_size, void* d_ws, size_t ws_size,
                              hipStream_t stream) {
    (void)n_in; (void)out_size; (void)ws_size;
    const float* x     = (const float*)d_in[0];
    const float* c1_w  = (const float*)d_in[1];
    const float* c1_b  = (const float*)d_in[2];
    const float* s2_w  = (const float*)d_in[3];
    const float* s2_b  = (const float*)d_in[4];
    const float* c3_w  = (const float*)d_in[5];
    const float* c3_b  = (const float*)d_in[6];
    const float* s4_w  = (const float*)d_in[7];
    const float* s4_b  = (const float*)d_in[8];
    const float* c5_w  = (const float*)d_in[9];
    const float* c5_b  = (const float*)d_in[10];
    const float* f6_w  = (const float*)d_in[11];
    const float* f6_b  = (const float*)d_in[12];
    const float* rbf_w = (const float*)d_in[13];
    float* out = (float*)d_out;
    float* ws  = (float*)d_ws;

    const int B = in_sizes[0] / 1024;   // 8192

    prep_kernel<<<256, 256, 0, stream>>>(c1_w, c1_b, s2_w, s2_b, c3_w, c3_b,
                                         s4_w, s4_b, c5_w, f6_w, rbf_w, ws);
    lenet_kernel<<<B / 4, 256, 0, stream>>>(x, c5_b, f6_b, ws, out);
}

// Round 5
// 133.515 us; speedup vs baseline: 1.0923x; 1.0122x over previous
//
#include <hip/hip_runtime.h>
#include <math.h>

// LeNet-5 fused forward, G=4 images per 256-thread block, 2048 blocks, all-MFMA.
// Round 16: K-slot permutation for phases B and C so each quad's im2col reads sit at
// CONSTANT dword offsets {0,1,2, 2P, 4P+1, 4P+2} from one per-lane base (P = row pitch
// in dwords: 18 for XPAD, 9 for S2H). The compiler merges them into ds_read2_b32:
// 6 scattered b32 -> 3 paired reads per MFMA-pair (~90 fewer LDS instrs/thread).
// Slot->window mapping (B-weights re-encoded in prep; dup/out-of-window slots = 0):
//   x32 quad q: j=0..5 -> win(q, j); j=6,7 -> win(q+2, j-6) real iff q>=2
//   x16 quad q: j=0..3 -> win(q+4, 2+j) real iff q<=1
// Guard region [19888,20080) zero-inited (out-of-window reads must be finite: 0*NaN=NaN).
typedef _Float16 h16;
typedef h16  h8v __attribute__((ext_vector_type(8)));
typedef h16  h4v __attribute__((ext_vector_type(4)));
typedef h16  h2v __attribute__((ext_vector_type(2)));
typedef float f4v __attribute__((ext_vector_type(4)));
typedef unsigned int u32;

// ws float offsets
#define WS_B1   0       // 6 f32
#define WS_B3   8       // 16 f32
#define WS_KB1  24      // [16][48] f16 (C1 B^T, slot layout) = 768 h16
#define WS_W3H  408     // [6][16][48] f16 (C3 B^T, slot layout) = 4608 h16
#define WS_W5H  2712    // [13][128][32] f16 (C5 B^T, K-packed kg=i*26+r, r<25 valid) = 53248 h16
#define WS_F6H  29336   // [96][128] f16 (F6 B^T, pads 0) = 12288 h16
#define WS_RBFT 35480   // 840 f32: rbf transposed [10][84]

// LDS byte offsets (8 barriers)
#define L_B3    0       // 64B
#define L_C5B   64      // 480B (120 f32)
#define L_F6B   544     // 336B (84 f32)
#define L_S2H   880     // 13824B [4][6][16][18] h16 (dead after C)
#define L_A5    880     // 13568B [16][424] h16 (over dead S2H)
#define L_HB    880     // 5632B  [16][88] f32 (over dead A5)
#define L_XPAD  14704   // 5184B: 2 imgs x [36][36] h16 (dead after B)
#define L_S4    14704   // 5376B [4][16][42] h16 (over dead XPAD)
#define L_A6    14704   // 4352B [16][136] h16 (over dead S4)
#define L_GUARD 19888   // 192B zero guard (covers out-of-window slot reads)
#define LDS_TOTAL 20080

__device__ const unsigned char MASK16[16] = {7,14,28,56,49,35,15,30,60,57,51,39,27,54,45,63};

// 1.7159*tanh((2/3)x) = 1.7159 - 3.4318/(1 + e^{(4/3)x})
__device__ __forceinline__ float squash(float x) {
    float E = __expf(1.33333333f * x);
    return 1.7159f - 3.4318f * __builtin_amdgcn_rcpf(1.0f + E);
}

// slot c (0..47) -> window (u,v); u=-1 means zero slot
__device__ __forceinline__ void slot_to_uv(int c, int& u, int& v) {
    u = -1; v = 0;
    if (c < 32) {
        int q = c >> 3, j = c & 7;
        if (j < 6)       { u = q;     v = j; }
        else if (q == 2) { u = 4;     v = j - 6; }
        else if (q == 3) { u = 5;     v = j - 6; }
    } else {
        int cc = c - 32, q = cc >> 2, j = cc & 3;
        if (q == 0)      { u = 4;     v = 2 + j; }
        else if (q == 1) { u = 5;     v = 2 + j; }
    }
}

__global__ __launch_bounds__(256) void prep_kernel(
    const float* __restrict__ c1_w, const float* __restrict__ c1_b,
    const float* __restrict__ s2_w, const float* __restrict__ s2_b,
    const float* __restrict__ c3_w, const float* __restrict__ c3_b,
    const float* __restrict__ s4_w, const float* __restrict__ s4_b,
    const float* __restrict__ c5_w, const float* __restrict__ f6_w,
    const float* __restrict__ rbf_w,
    float* __restrict__ ws)
{
    const int gid = blockIdx.x * 256 + threadIdx.x;
    const int gstr = gridDim.x * 256;
    if (gid < 6)  ws[WS_B1 + gid] = s2_w[gid] * c1_b[gid] + s2_b[gid];
    if (gid < 16) ws[WS_B3 + gid] = s4_w[gid] * c3_b[gid] + s4_b[gid];
    // KB1: [16 n][48 slots] B^T for C1+S2 folded conv
    h16* KB1 = (h16*)(ws + WS_KB1);
    for (int idx = gid; idx < 768; idx += gstr) {
        int n = idx / 48, c = idx - n * 48;
        int u, v; slot_to_uv(c, u, v);
        float val = 0.f;
        if (n < 6 && u >= 0) {
            float s = 0.f;
            #pragma unroll
            for (int dy = 0; dy < 2; ++dy)
                #pragma unroll
                for (int dx = 0; dx < 2; ++dx) {
                    int ky = u - dy, kx = v - dx;
                    if (ky >= 0 && ky < 5 && kx >= 0 && kx < 5)
                        s += c1_w[(n * 5 + ky) * 5 + kx];
                }
            val = 0.25f * s * s2_w[n];
        }
        KB1[idx] = (h16)val;
    }
    // W3H: [6 i][16 n][48 slots]
    h16* W3H = (h16*)(ws + WS_W3H);
    for (int idx = gid; idx < 4608; idx += gstr) {
        int i = idx / 768, r = idx - i * 768;
        int n = r / 48, c = r - n * 48;
        int u, v; slot_to_uv(c, u, v);
        float val = 0.f;
        if (u >= 0) {
            float s = 0.f;
            #pragma unroll
            for (int dy = 0; dy < 2; ++dy)
                #pragma unroll
                for (int dx = 0; dx < 2; ++dx) {
                    int ky = u - dy, kx = v - dx;
                    if (ky >= 0 && ky < 5 && kx >= 0 && kx < 5)
                        s += c3_w[((n * 6 + i) * 5 + ky) * 5 + kx];
                }
            val = ((MASK16[n] >> i) & 1) ? 0.25f * s4_w[n] * s : 0.f;
        }
        W3H[idx] = (h16)val;
    }
    // C5 weights K-packed pitch 26: kg = kb*32+k; i = kg/26, r = kg%26; r<25 valid
    h16* W5H = (h16*)(ws + WS_W5H);
    for (int idx = gid; idx < 53248; idx += gstr) {
        int kb = idx >> 12, rr = idx & 4095;
        int n = rr >> 5, k = rr & 31;
        int kg = kb * 32 + k;
        int i = kg / 26, r = kg - i * 26;
        float val = (n < 120 && r < 25) ? c5_w[n * 400 + i * 25 + r] : 0.f;
        W5H[idx] = (h16)val;
    }
    h16* F6H = (h16*)(ws + WS_F6H);
    for (int idx = gid; idx < 12288; idx += gstr) {
        int n = idx >> 7, k = idx & 127;
        float val = (n < 84 && k < 120) ? f6_w[n * 120 + k] : 0.f;
        F6H[idx] = (h16)val;
    }
    for (int idx = gid; idx < 840; idx += gstr) {
        int k = idx / 10, c = idx - k * 10;
        ws[WS_RBFT + c * 84 + k] = rbf_w[idx];
    }
}

__global__ __launch_bounds__(256, 8) void lenet_kernel(
    const float* __restrict__ x,
    const float* __restrict__ c5_b, const float* __restrict__ f6_b,
    const float* __restrict__ ws,
    float* __restrict__ out)
{
    __shared__ __align__(16) char smem[LDS_TOTAL];
    float* s_b3  = (float*)(smem + L_B3);
    float* s_c5b = (float*)(smem + L_C5B);
    float* s_f6b = (float*)(smem + L_F6B);
    h16*  XPAD   = (h16*)(smem + L_XPAD);
    h16*  S2H    = (h16*)(smem + L_S2H);
    h16*  S4     = (h16*)(smem + L_S4);
    h16*  A5     = (h16*)(smem + L_A5);
    h16*  A6     = (h16*)(smem + L_A6);
    float* HB    = (float*)(smem + L_HB);

    const int tid  = threadIdx.x;
    const int wave = __builtin_amdgcn_readfirstlane(tid >> 6);
    const int lane = tid & 63;
    const int quad = lane >> 4;
    const int lr   = lane & 15;

    // ---- stage consts; zero guard; load B-frags for phase B once (6 VGPRs) ----
    if (tid < 16)  s_b3[tid] = ws[WS_B3 + tid];
    if (tid < 120) s_c5b[tid] = c5_b[tid];
    if (tid < 84)  s_f6b[tid] = f6_b[tid];
    if (tid < 48)  ((u32*)(smem + L_GUARD))[tid] = 0u;
    const float* xb = x + (size_t)blockIdx.x * 4096;
    const h16* KB1 = (const h16*)(ws + WS_KB1);
    h8v w1a = *(const h8v*)(KB1 + lr * 48 + quad * 8);
    h4v w1b = *(const h4v*)(KB1 + lr * 48 + 32 + quad * 4);
    float b1v = ws[WS_B1 + (lr < 6 ? lr : 0)];

    // phase A stage: load imgs (2s, 2s+1) into XPAD with replicate pad
    auto stageA = [&](int s) {
        #pragma unroll
        for (int k = 0; k < 2; ++k) {
            int idx = tid + k * 256;            // 0..511: interior 2x32x8 float4
            int im = idx >> 8;
            int r  = (idx >> 3) & 31;
            int c4 = idx & 7;
            float4 v = *(const float4*)(xb + (2 * s + im) * 1024 + r * 32 + c4 * 4);
            h2v p0; p0.x = (h16)v.x; p0.y = (h16)v.y;
            h2v p1; p1.x = (h16)v.z; p1.y = (h16)v.w;
            h16* d = XPAD + im * 1296 + (r + 2) * 36 + (4 * c4 + 2);
            *(h2v*)(d)     = p0;
            *(h2v*)(d + 2) = p1;
        }
        #pragma unroll
        for (int k = 0; k < 3; ++k) {
            int e = tid + k * 256;              // 544 halo cells (3 passes)
            if (e < 544) {
                int im = (e >= 272) ? 1 : 0;
                int h = e - 272 * im;
                int u, v;
                if (h < 144) { int q = h / 36; u = (q < 2) ? q : 32 + q; v = h - q * 36; }
                else { int g = h - 144; u = 2 + (g >> 2); int q = g & 3; v = (q < 2) ? q : 32 + q; }
                int sr = min(max(u - 2, 0), 31), sc = min(max(v - 2, 0), 31);
                XPAD[im * 1296 + u * 36 + v] = (h16)xb[(2 * s + im) * 1024 + sr * 32 + sc];
            }
        }
    };

    // phase B stage: C1+S2+act via MFMA im2col, slot-permuted reads (P = 18 dwords)
    auto stageB = [&](int s) {
        const h16* bp = XPAD + (wave >> 1) * 1296 + (wave & 1) * 576 + 2 * lr;
        h16* s2base = S2H + (s * 2 + (wave >> 1)) * 1728 + lr * 288 + (wave & 1) * 144 + quad * 4;
        #pragma unroll
        for (int tt = 0; tt < 8; ++tt) {
            const u32* bq = (const u32*)bp + quad * 18;
            union { u32 u[4]; h8v h; } av;
            av.u[0] = bq[0];  av.u[1] = bq[1];
            av.u[2] = bq[2];  av.u[3] = bq[36];
            f4v acc = {b1v, b1v, b1v, b1v};
            acc = __builtin_amdgcn_mfma_f32_16x16x32_f16(av.h, w1a, acc, 0, 0, 0);
            union { u32 u[2]; h4v h; } av2;
            av2.u[0] = bq[73]; av2.u[1] = bq[74];
            acc = __builtin_amdgcn_mfma_f32_16x16x16f16(av2.h, w1b, acc, 0, 0, 0);
            if (lr < 6) {
                h2v q0; q0.x = (h16)squash(acc[0]); q0.y = (h16)squash(acc[1]);
                h2v q1; q1.x = (h16)squash(acc[2]); q1.y = (h16)squash(acc[3]);
                *(h2v*)(s2base + tt * 18)     = q0;
                *(h2v*)(s2base + tt * 18 + 2) = q1;
            }
            bp += 72;
        }
    };

    stageA(0);
    __syncthreads();   // [1] XPAD(0,1) + consts + guard ready
    stageB(0);
    __syncthreads();   // [2] XPAD(0,1) reads done
    stageA(1);
    __syncthreads();   // [3] XPAD(2,3) ready
    stageB(1);
    __syncthreads();   // [4] S2H ready; XPAD dead

    // ======== C: C3+S4 via MFMA, slot-permuted reads from S2H (P = 9 dwords) ========
    {
        const h16* W3H = (const h16*)(ws + WS_W3H);
        int baseh0, baseh1, baseh2;
        {
            int m0 = wave * 16 + lr;
            int i0 = m0 / 36, p0 = m0 - i0 * 36;
            baseh0 = i0 * 1728 + (2 * (p0 / 6)) * 18 + 2 * (p0 % 6);
            int m1 = (wave + 4) * 16 + lr;
            int i1 = m1 / 36, p1 = m1 - i1 * 36;
            baseh1 = i1 * 1728 + (2 * (p1 / 6)) * 18 + 2 * (p1 % 6);
            int m2 = 128 + lr;   // Mt=8 (wave 0 only)
            int i2 = m2 / 36, p2 = m2 - i2 * 36;
            baseh2 = i2 * 1728 + (2 * (p2 / 6)) * 18 + 2 * (p2 % 6);
        }
        float b3v = s_b3[lr];
        f4v cinit = {b3v, b3v, b3v, b3v};
        f4v cacc0 = cinit, cacc1 = cinit, cacc2 = cinit;
        const bool w0 = (wave == 0);
        #pragma unroll
        for (int i = 0; i < 6; ++i) {
            const h16* bbase = W3H + i * 768 + lr * 48;
            h8v w3a = *(const h8v*)(bbase + quad * 8);
            h4v w3b = *(const h4v*)(bbase + 32 + quad * 4);
            {
                const u32* cq = (const u32*)(S2H + baseh0 + i * 288) + quad * 9;
                union { u32 u[4]; h8v h; } av;
                av.u[0] = cq[0];  av.u[1] = cq[1];
                av.u[2] = cq[2];  av.u[3] = cq[18];
                cacc0 = __builtin_amdgcn_mfma_f32_16x16x32_f16(av.h, w3a, cacc0, 0, 0, 0);
                union { u32 u[2]; h4v h; } av2;
                av2.u[0] = cq[37]; av2.u[1] = cq[38];
                cacc0 = __builtin_amdgcn_mfma_f32_16x16x16f16(av2.h, w3b, cacc0, 0, 0, 0);
            }
            {
                const u32* cq = (const u32*)(S2H + baseh1 + i * 288) + quad * 9;
                union { u32 u[4]; h8v h; } av;
                av.u[0] = cq[0];  av.u[1] = cq[1];
                av.u[2] = cq[2];  av.u[3] = cq[18];
                cacc1 = __builtin_amdgcn_mfma_f32_16x16x32_f16(av.h, w3a, cacc1, 0, 0, 0);
                union { u32 u[2]; h4v h; } av2;
                av2.u[0] = cq[37]; av2.u[1] = cq[38];
                cacc1 = __builtin_amdgcn_mfma_f32_16x16x16f16(av2.h, w3b, cacc1, 0, 0, 0);
            }
            if (w0) {
                const u32* cq = (const u32*)(S2H + baseh2 + i * 288) + quad * 9;
                union { u32 u[4]; h8v h; } av;
                av.u[0] = cq[0];  av.u[1] = cq[1];
                av.u[2] = cq[2];  av.u[3] = cq[18];
                cacc2 = __builtin_amdgcn_mfma_f32_16x16x32_f16(av.h, w3a, cacc2, 0, 0, 0);
                union { u32 u[2]; h4v h; } av2;
                av2.u[0] = cq[37]; av2.u[1] = cq[38];
                cacc2 = __builtin_amdgcn_mfma_f32_16x16x16f16(av2.h, w3b, cacc2, 0, 0, 0);
            }
        }
        // epilogue: squash -> S4 (over dead XPAD)
        {
            #pragma unroll
            for (int r = 0; r < 4; ++r) {
                int m = wave * 16 + quad * 4 + r;
                int img = m / 36, pos = m - img * 36;
                S4[img * 672 + lr * 42 + pos] = (h16)squash(cacc0[r]);
            }
            #pragma unroll
            for (int r = 0; r < 4; ++r) {
                int m = (wave + 4) * 16 + quad * 4 + r;
                int img = m / 36, pos = m - img * 36;
                S4[img * 672 + lr * 42 + pos] = (h16)squash(cacc1[r]);
            }
            if (w0) {
                #pragma unroll
                for (int r = 0; r < 4; ++r) {
                    int m = 128 + quad * 4 + r;
                    int img = m / 36, pos = m - img * 36;
                    S4[img * 672 + lr * 42 + pos] = (h16)squash(cacc2[r]);
                }
            }
        }
    }
    __syncthreads();   // [5] S4 ready; all S2H reads done

    // ======== D: C5 via MFMA. GEMM [16 x 416] x [416 x 128], K-packed pitch 26 ========
    {
        // build A5 [16][424] (over dead S2H): thread = (m, i); A5[m][i*26+k] = window val
        {
            int m = tid >> 4, i = tid & 15;
            int img = m >> 2, q = m & 3, qy = q >> 1, qx = q & 1;
            const h16* s4b = S4 + img * 672 + i * 42 + qy * 6 + qx;
            u32* dst = (u32*)(A5 + m * 424 + i * 26);
            #pragma unroll
            for (int w = 0; w < 12; ++w) {
                int k0 = 2 * w, k1 = 2 * w + 1;
                union { h2v h; u32 u; } p;
                p.h.x = s4b[(k0 / 5) * 6 + (k0 % 5)];
                p.h.y = s4b[(k1 / 5) * 6 + (k1 % 5)];
                dst[w] = p.u;
            }
            {
                union { h2v h; u32 u; } p;
                p.h.x = s4b[28];  // k=24 -> (4,4)
                p.h.y = (h16)0.f;
                dst[12] = p.u;
            }
        }
        __syncthreads();   // [6] A5 ready
        const h16* W5H = (const h16*)(ws + WS_W5H);
        float c5b0 = s_c5b[wave * 32 + lr];
        float c5b1 = s_c5b[wave * 32 + 16 + lr];   // may over-read into F6B consts; discarded
        f4v dacc0 = {c5b0, c5b0, c5b0, c5b0};
        f4v dacc1 = {c5b1, c5b1, c5b1, c5b1};
        #pragma unroll
        for (int i = 0; i < 13; ++i) {
            h8v bf0 = *(const h8v*)(W5H + i * 4096 + (wave * 32 + lr) * 32 + quad * 8);
            h8v bf1 = *(const h8v*)(W5H + i * 4096 + (wave * 32 + 16 + lr) * 32 + quad * 8);
            h8v af0 = *(const h8v*)(A5 + lr * 424 + i * 32 + quad * 8);
            dacc0 = __builtin_amdgcn_mfma_f32_16x16x32_f16(af0, bf0, dacc0, 0, 0, 0);
            dacc1 = __builtin_amdgcn_mfma_f32_16x16x32_f16(af0, bf1, dacc1, 0, 0, 0);
        }
        // zero pad cols 120..127 of A6 (over dead S4)
        if (tid < 64) {
            int m = tid >> 2, j = tid & 3;
            *(u32*)(A6 + m * 136 + 120 + 2 * j) = 0u;
        }
        // epilogue, reference reshape: row=img*4+(n/30), col=(n%30)*4+q
        {
            int n0 = wave * 32 + lr;
            if (n0 < 120) {
                int tt = n0 / 30, cb = (n0 - tt * 30) * 4;
                #pragma unroll
                for (int r = 0; r < 4; ++r) {
                    int m = quad * 4 + r;
                    A6[((m >> 2) * 4 + tt) * 136 + cb + (m & 3)] = (h16)dacc0[r];
                }
            }
            int n1 = wave * 32 + 16 + lr;
            if (n1 < 120) {
                int tt = n1 / 30, cb = (n1 - tt * 30) * 4;
                #pragma unroll
                for (int r = 0; r < 4; ++r) {
                    int m = quad * 4 + r;
                    A6[((m >> 2) * 4 + tt) * 136 + cb + (m & 3)] = (h16)dacc1[r];
                }
            }
        }
    }
    __syncthreads();   // [7] A6 ready; all A5 reads done

    // ======== E: F6+act via MFMA. GEMM [16 x 128] x [128 x 96] ========
    {
        const h16* F6H = (const h16*)(ws + WS_F6H);
        float f60 = s_f6b[wave * 16 + lr];
        f4v eacc0 = {f60, f60, f60, f60};
        f4v eacc1 = {};
        const bool w2 = (wave < 2);
        if (w2) {
            int n1 = (wave + 4) * 16 + lr;
            float f61 = (n1 < 84) ? s_f6b[n1] : 0.f;
            eacc1[0] = f61; eacc1[1] = f61; eacc1[2] = f61; eacc1[3] = f61;
        }
        #pragma unroll
        for (int kc = 0; kc < 4; ++kc) {
            h8v a8 = *(const h8v*)(A6 + lr * 136 + kc * 32 + quad * 8);
            h8v b0 = *(const h8v*)(F6H + (wave * 16 + lr) * 128 + kc * 32 + quad * 8);
            eacc0 = __builtin_amdgcn_mfma_f32_16x16x32_f16(a8, b0, eacc0, 0, 0, 0);
            if (w2) {
                h8v b1 = *(const h8v*)(F6H + ((wave + 4) * 16 + lr) * 128 + kc * 32 + quad * 8);
                eacc1 = __builtin_amdgcn_mfma_f32_16x16x32_f16(a8, b1, eacc1, 0, 0, 0);
            }
        }
        {
            int n = wave * 16 + lr;   // 0..63 < 84
            #pragma unroll
            for (int r = 0; r < 4; ++r) {
                int m = quad * 4 + r;
                HB[m * 88 + n] = squash(eacc0[r]);   // HB over dead A5
            }
        }
        if (w2) {
            int n = (wave + 4) * 16 + lr;  // 64..95
            if (n < 84) {
                #pragma unroll
                for (int r = 0; r < 4; ++r) {
                    int m = quad * 4 + r;
                    HB[m * 88 + n] = squash(eacc1[r]);
                }
            }
        }
    }
    __syncthreads();   // [8] HB ready

    // ======== F: RBF distances (VALU); prototypes from L2-resident rbfT ========
    if (tid < 160) {
        int m = tid / 10, cls = tid - m * 10;
        const float4* hr = (const float4*)(HB + m * 88);
        const float4* pr = (const float4*)(ws + WS_RBFT + cls * 84);
        float a = 0.f;
        #pragma unroll
        for (int u = 0; u < 21; ++u) {
            float4 hv = hr[u], pv = pr[u];
            float dx = hv.x - pv.x, dy = hv.y - pv.y;
            float dz = hv.z - pv.z, dw = hv.w - pv.w;
            a += dx * dx + dy * dy + dz * dz + dw * dw;
        }
        out[(size_t)blockIdx.x * 160 + tid] = a;
    }
}

extern "C" void kernel_launch(void* const* d_in, const int* in_sizes, int n_in,
                              void* d_out, int out_size, void* d_ws, size_t ws_size,
                              hipStream_t stream) {
    (void)n_in; (void)out_size; (void)ws_size;
    const float* x     = (const float*)d_in[0];
    const float* c1_w  = (const float*)d_in[1];
    const float* c1_b  = (const float*)d_in[2];
    const float* s2_w  = (const float*)d_in[3];
    const float* s2_b  = (const float*)d_in[4];
    const float* c3_w  = (const float*)d_in[5];
    const float* c3_b  = (const float*)d_in[6];
    const float* s4_w  = (const float*)d_in[7];
    const float* s4_b  = (const float*)d_in[8];
    const float* c5_w  = (const float*)d_in[9];
    const float* c5_b  = (const float*)d_in[10];
    const float* f6_w  = (const float*)d_in[11];
    const float* f6_b  = (const float*)d_in[12];
    const float* rbf_w = (const float*)d_in[13];
    float* out = (float*)d_out;
    float* ws  = (float*)d_ws;

    const int B = in_sizes[0] / 1024;   // 8192

    prep_kernel<<<256, 256, 0, stream>>>(c1_w, c1_b, s2_w, s2_b, c3_w, c3_b,
                                         s4_w, s4_b, c5_w, f6_w, rbf_w, ws);
    lenet_kernel<<<B / 4, 256, 0, stream>>>(x, c5_b, f6_b, ws, out);
}